// Round 13
// baseline (635.643 us; speedup 1.0000x reference)
//
#include <hip/hip_runtime.h>
#include <math.h>

// V=4096, E=12288, NI=3900, B=64
#define NI_   3900
#define NIPP  4096
#define E_    12288
#define B_    64
#define V_    4096
#define NIT   8               // CG iterations (absmax 1.22e-3 vs thr 2.02e-3)
#define KS_   8               // k-splits in CG matvec (512 k each)
#define TRI   31              // live 128-tiles per dim (rows >= 3968 are zero)
#define NTILE 496             // TRI*(TRI+1)/2, = 8*62 (bijective XCD swizzle)
#define KHALF 6144            // E/2 per gemm k-split

typedef _Float16 f16x8 __attribute__((ext_vector_type(8)));
typedef _Float16 f16x4 __attribute__((ext_vector_type(4)));
typedef float    f32x4 __attribute__((ext_vector_type(4)));

__device__ __forceinline__ void gload16(const void* g, void* lds) {
    __builtin_amdgcn_global_load_lds(
        (const __attribute__((address_space(1))) unsigned int*)g,
        (__attribute__((address_space(3))) unsigned int*)lds, 16, 0, 0);
}

// wg (0..495) -> upper-triangular tile (bi, bj) over 31x31, XCD-swizzled
__device__ __forceinline__ void tile_of(int wg, int& bi, int& bj) {
    int swz = (wg & 7) * 62 + (wg >> 3);        // 496 = 8*62, bijective
    int b = 0, rem = swz;
    while (rem >= TRI - b) { rem -= TRI - b; ++b; }
    bi = b; bj = b + rem;
}

// ---------------------------------------------------------------------------
// AT[i][k] = f16( sqrt(w[k]) * d0[k, ii[i]] ), zero for i >= NI_.
__global__ __launch_bounds__(256) void k_conv(const float* __restrict__ d0,
                                              const float* __restrict__ w,
                                              const int* __restrict__ ii,
                                              _Float16* __restrict__ AT) {
    __shared__ _Float16 Ls[64][65];
    int k0 = blockIdx.x * 64, i0 = blockIdx.y * 64;
    int t = threadIdx.x;
    int kr = t >> 4, ic = (t & 15) * 4;
    int g[4];
#pragma unroll
    for (int u = 0; u < 4; ++u) {
        int i = i0 + ic + u;
        g[u] = (i < NI_) ? ii[i] : -1;
    }
    bool cont = (g[0] >= 0) && (g[3] == g[0] + 3) && ((g[0] & 3) == 0);
#pragma unroll
    for (int p = 0; p < 4; ++p) {
        int k = k0 + p * 16 + kr;
        float s = sqrtf(w[k]);
        const float* row = d0 + (size_t)k * V_;
        if (cont) {
            float4 v4 = *(const float4*)&row[g[0]];
            Ls[p * 16 + kr][ic + 0] = (_Float16)(s * v4.x);
            Ls[p * 16 + kr][ic + 1] = (_Float16)(s * v4.y);
            Ls[p * 16 + kr][ic + 2] = (_Float16)(s * v4.z);
            Ls[p * 16 + kr][ic + 3] = (_Float16)(s * v4.w);
        } else {
#pragma unroll
            for (int u = 0; u < 4; ++u)
                Ls[p * 16 + kr][ic + u] = (_Float16)(g[u] >= 0 ? s * row[g[u]] : 0.f);
        }
    }
    __syncthreads();
    int ir = t >> 3, kc = (t & 7) * 8;
#pragma unroll
    for (int p = 0; p < 2; ++p) {
        int i = p * 32 + ir;
        f16x8 v;
#pragma unroll
        for (int j = 0; j < 8; ++j) v[j] = Ls[kc + j][i];
        *(f16x8*)&AT[(size_t)(i0 + i) * E_ + k0 + kc] = v;
    }
}

// ---------------------------------------------------------------------------
// Partial S: Pbuf[ks][wg][r][c] = sum_{k in split ks} AT[gi+r,k]*AT[gj+c,k].
// Double-buffered LDS: STAGE(t+1) issued BEFORE compute(t); ONE barrier per
// K-step placed AFTER the MFMAs so the vmcnt(0) drain overlaps compute.
__global__ __launch_bounds__(256) void k_gpart(const _Float16* __restrict__ AT,
                                               _Float16* __restrict__ Pbuf) {
    int bi, bj; tile_of(blockIdx.x, bi, bj);
    int ks = blockIdx.y;

    __shared__ _Float16 TA[2][128 * 64];   // 2 x 16KB
    __shared__ _Float16 TB[2][128 * 64];   // 2 x 16KB  (64KB total)
    int t = threadIdx.x, l = t & 63, w = t >> 6;
    int gi = bi * 128, gj = bj * 128;
    int wr = (w >> 1) * 64, wc = (w & 1) * 64;
    int lr = l >> 3, lc = (l & 7) * 8;

    f32x4 acc[4][4] = {};
    const int NKT = KHALF / 64;            // 96 K-steps
    int kbase = ks * KHALF;

#define STAGE(BUF, K0)                                                         \
    {                                                                          \
        _Pragma("unroll")                                                      \
        for (int inst = 0; inst < 4; ++inst) {                                 \
            int row = w * 32 + inst * 8;                                       \
            gload16(&AT[(size_t)(gi + row + lr) * E_ + (K0) + lc],             \
                    &TA[BUF][row * 64]);                                       \
            gload16(&AT[(size_t)(gj + row + lr) * E_ + (K0) + lc],             \
                    &TB[BUF][row * 64]);                                       \
        }                                                                      \
    }

    STAGE(0, kbase);
    __syncthreads();                       // buf0 landed for all waves

    for (int kt = 0; kt < NKT; ++kt) {
        int cur = kt & 1;
        if (kt + 1 < NKT) STAGE(cur ^ 1, kbase + (kt + 1) * 64);  // flies during MFMA
#pragma unroll
        for (int kk = 0; kk < 2; ++kk) {
            int ko = kk * 32 + (l >> 4) * 8;
            f16x8 a[4], b[4];
#pragma unroll
            for (int f = 0; f < 4; ++f) {
                a[f] = *(const f16x8*)&TA[cur][(wr + f * 16 + (l & 15)) * 64 + ko];
                b[f] = *(const f16x8*)&TB[cur][(wc + f * 16 + (l & 15)) * 64 + ko];
            }
#pragma unroll
            for (int fm = 0; fm < 4; ++fm)
#pragma unroll
                for (int fn = 0; fn < 4; ++fn)
                    acc[fm][fn] = __builtin_amdgcn_mfma_f32_16x16x32_f16(
                        a[fm], b[fn], acc[fm][fn], 0, 0, 0);
        }
        __syncthreads();   // drains next-tile stage (post-MFMA) + guards buf reuse
    }
#undef STAGE

    _Float16* P = Pbuf + ((size_t)ks * NTILE + blockIdx.x) * 16384;
#pragma unroll
    for (int fm = 0; fm < 4; ++fm)
#pragma unroll
        for (int fn = 0; fn < 4; ++fn)
#pragma unroll
            for (int q = 0; q < 4; ++q) {
                int r = wr + fm * 16 + (l >> 4) * 4 + q;
                int c = wc + fn * 16 + (l & 15);
                P[r * 128 + c] = (_Float16)acc[fm][fn][q];
            }
}

// Combine partials, add diagonal, write Sh tile + LDS-transposed mirror.
__global__ __launch_bounds__(256) void k_comb(const _Float16* __restrict__ Pbuf,
                                              const float* __restrict__ s0i,
                                              const int* __restrict__ ii,
                                              _Float16* __restrict__ Sh) {
    __shared__ _Float16 L[128][129];
    int wg = blockIdx.x;
    int bi, bj; tile_of(wg, bi, bj);
    int gi = bi * 128, gj = bj * 128;
    int t = threadIdx.x;
    const _Float16* P0 = Pbuf + (size_t)wg * 16384;
    const _Float16* P1 = Pbuf + ((size_t)NTILE + wg) * 16384;
#pragma unroll
    for (int rep = 0; rep < 16; ++rep) {
        int idx = rep * 1024 + t * 4;
        int r = idx >> 7, c = idx & 127;
        f16x4 a = *(const f16x4*)&P0[idx];
        f16x4 b = *(const f16x4*)&P1[idx];
        f16x4 h;
#pragma unroll
        for (int u = 0; u < 4; ++u) {
            float v = (float)a[u] + (float)b[u];
            if (bi == bj && r == c + u && gi + r < NI_)
                v += 1.0f / s0i[ii[gi + r]];
            h[u] = (_Float16)v;
            L[r][c + u] = h[u];
        }
        *(f16x4*)&Sh[(size_t)(gi + r) * NIPP + gj + c] = h;
    }
    if (bi != bj) {
        __syncthreads();
#pragma unroll
        for (int rep = 0; rep < 16; ++rep) {
            int idx = rep * 1024 + t * 4;
            int r = idx >> 7, c = idx & 127;
            f16x4 h;
#pragma unroll
            for (int u = 0; u < 4; ++u) h[u] = L[c + u][r];
            *(f16x4*)&Sh[(size_t)(gj + r) * NIPP + gi + c] = h;
        }
    }
}

// ---------------------------------------------------------------------------
// c-major init: block c. r = X[c,ii]/s0i[ii]; phT = f16(r); x = 0; rr[c]=||r||^2
__global__ __launch_bounds__(256) void k_init(const float* __restrict__ X,
                                              const float* __restrict__ s0i,
                                              const int* __restrict__ ii,
                                              float* __restrict__ r,
                                              _Float16* __restrict__ phT,
                                              float* __restrict__ x,
                                              float* __restrict__ rr) {
    __shared__ float red[4];
    int c = blockIdx.x, t = threadIdx.x;
    float acc = 0.f;
    for (int i = t; i < NIPP; i += 256) {
        float v = 0.f;
        if (i < NI_) { int g = ii[i]; v = X[(size_t)c * V_ + g] / s0i[g]; }
        size_t o = (size_t)c * NIPP + i;
        r[o] = v; phT[o] = (_Float16)v; x[o] = 0.f;
        acc += v * v;
    }
#pragma unroll
    for (int s = 32; s; s >>= 1) acc += __shfl_down(acc, s, 64);
    if ((t & 63) == 0) red[t >> 6] = acc;
    __syncthreads();
    if (t == 0) rr[c] = red[0] + red[1] + red[2] + red[3];
}

// part[ks][c][i] (f16) = Sh-slice @ p; pAp partials -> papB. Non-atomic.
__global__ __launch_bounds__(256) void k_mv(const _Float16* __restrict__ Sh,
                                            const _Float16* __restrict__ phT,
                                            _Float16* __restrict__ part,
                                            float* __restrict__ papB) {
    __shared__ float papL[4][64];
    int rt = blockIdx.x, ks = blockIdx.y;
    int b = ks * 64 + rt;
    int t = threadIdx.x, l = t & 63, w = t >> 6;
    int r0 = rt * 64 + w * 16;
    int lrow = l & 15, lko = (l >> 4) * 8;
    const _Float16* arow = Sh + (size_t)(r0 + lrow) * NIPP + ks * 512 + lko;
    f32x4 acc[4] = {};
#pragma unroll 4
    for (int kk = 0; kk < 16; ++kk) {
        f16x8 a = *(const f16x8*)(arow + kk * 32);
#pragma unroll
        for (int fn = 0; fn < 4; ++fn) {
            f16x8 bb = *(const f16x8*)&phT[(size_t)(fn * 16 + lrow) * NIPP +
                                           ks * 512 + kk * 32 + lko];
            acc[fn] = __builtin_amdgcn_mfma_f32_16x16x32_f16(a, bb, acc[fn], 0, 0, 0);
        }
    }
    float papv[4];
#pragma unroll
    for (int fn = 0; fn < 4; ++fn) {
        int cc = fn * 16 + lrow;
        int ro = r0 + (l >> 4) * 4;
        f16x4 h;
#pragma unroll
        for (int u = 0; u < 4; ++u) h[u] = (_Float16)acc[fn][u];
        *(f16x4*)&part[(size_t)(ks * 64 + cc) * NIPP + ro] = h;
        f16x4 pv = *(const f16x4*)&phT[(size_t)cc * NIPP + ro];
        float d = (float)pv[0] * acc[fn][0] + (float)pv[1] * acc[fn][1] +
                  (float)pv[2] * acc[fn][2] + (float)pv[3] * acc[fn][3];
        d += __shfl_xor(d, 16, 64);
        d += __shfl_xor(d, 32, 64);
        papv[fn] = d;
    }
    if (l < 16) {
#pragma unroll
        for (int fn = 0; fn < 4; ++fn) papL[w][fn * 16 + l] = papv[fn];
    }
    __syncthreads();
    if (t < 64)
        papB[(size_t)t * 512 + b] = papL[0][t] + papL[1][t] + papL[2][t] + papL[3][t];
}

// One 1024-thread block per column c: single float4 pass, registers carried.
// i >= NI_ is masked to keep padded r/p exactly zero.
__global__ __launch_bounds__(1024) void k_fused(const _Float16* __restrict__ part,
                                                const float* __restrict__ papB,
                                                _Float16* __restrict__ phT,
                                                float* __restrict__ x,
                                                float* __restrict__ r,
                                                float* __restrict__ rr,
                                                float* __restrict__ out,
                                                int last) {
    __shared__ float redA[16], redB[16];
    int c = blockIdx.x, t = threadIdx.x, l = t & 63, w = t >> 6;
    size_t cb = (size_t)c * NIPP;
    float rro = rr[c];

    float pv2 = (t < 512) ? papB[(size_t)c * 512 + t] : 0.f;
#pragma unroll
    for (int s = 32; s; s >>= 1) pv2 += __shfl_down(pv2, s, 64);
    if (l == 0) redA[w] = pv2;
    __syncthreads();
    float pap = 0.f;
#pragma unroll
    for (int k = 0; k < 16; ++k) pap += redA[k];
    float alpha = rro / (pap + 1e-30f);

    int i0 = t * 4;                          // 1024 thr x 4 = NIPP, one pass
    float sp[4] = {0.f, 0.f, 0.f, 0.f};
#pragma unroll
    for (int ks = 0; ks < KS_; ++ks) {
        f16x4 s4 = *(const f16x4*)&part[(size_t)(ks * 64 + c) * NIPP + i0];
#pragma unroll
        for (int u = 0; u < 4; ++u) sp[u] += (float)s4[u];
    }
    f16x4 p4 = *(const f16x4*)&phT[cb + i0];
    float4 x4 = *(const float4*)&x[cb + i0];
    float4 r4 = *(const float4*)&r[cb + i0];
    float pv[4] = {(float)p4[0], (float)p4[1], (float)p4[2], (float)p4[3]};
    float rv[4] = {r4.x, r4.y, r4.z, r4.w};
    float xn[4], rn[4];
    float rracc = 0.f;
#pragma unroll
    for (int u = 0; u < 4; ++u) {
        bool live = (i0 + u) < NI_;
        xn[u] = live ? (((const float*)&x4)[u] + alpha * pv[u]) : 0.f;
        rn[u] = live ? (rv[u] - alpha * sp[u]) : 0.f;
        rracc += rn[u] * rn[u];
    }
    if (last) {
        if (i0 + 3 < NI_) {   // NI_ = 3900: threads t<975 write, rest skip
            float4 o4 = make_float4(xn[0], xn[1], xn[2], xn[3]);
            *(float4*)&out[(size_t)c * NI_ + i0] = o4;
        }
    } else {
        *(float4*)&x[cb + i0] = make_float4(xn[0], xn[1], xn[2], xn[3]);
        *(float4*)&r[cb + i0] = make_float4(rn[0], rn[1], rn[2], rn[3]);
#pragma unroll
        for (int s = 32; s; s >>= 1) rracc += __shfl_down(rracc, s, 64);
        if (l == 0) redB[w] = rracc;
        __syncthreads();
        float rrn = 0.f;
#pragma unroll
        for (int k = 0; k < 16; ++k) rrn += redB[k];
        if (t == 0) rr[c] = rrn;
        float beta = rrn / (rro + 1e-30f);
        f16x4 pn;
#pragma unroll
        for (int u = 0; u < 4; ++u) pn[u] = (_Float16)(rn[u] + beta * pv[u]);
        *(f16x4*)&phT[cb + i0] = pn;
    }
}

// ---------------------------------------------------------------------------
extern "C" void kernel_launch(void* const* d_in, const int* in_sizes, int n_in,
                              void* d_out, int out_size, void* d_ws, size_t ws_size,
                              hipStream_t stream) {
    const float* X   = (const float*)d_in[0];
    const float* d0  = (const float*)d_in[1];
    const float* w   = (const float*)d_in[2];
    const float* s0i = (const float*)d_in[3];
    const int*   ii  = (const int*)d_in[4];
    float* out = (float*)d_out;

    char* ws = (char*)d_ws;
    // Region A [0, szA): AT during build; then Sh (33.5MB) + part + papB.
    // Region B [szA, szA+szPbuf): Pbuf during build; then phT/x/r/rr.
    size_t szA = (size_t)NIPP * E_ * 2;                       // 100,663,296
    size_t szPbuf = (size_t)2 * NTILE * 16384 * 2;            //  32,505,856
    if (ws_size < szA + szPbuf) return;  // clean failure signal

    _Float16* AT = (_Float16*)ws;
    _Float16* Pbuf = (_Float16*)(ws + szA);

    _Float16* Sh = (_Float16*)ws;                             // aliases AT (dead)
    _Float16* part = (_Float16*)(ws + (size_t)34 * 1048576);  // 4MB f16, in A
    float* papB = (float*)(part + (size_t)KS_ * 64 * NIPP);   // 128KB

    char* bB = ws + szA;                                      // aliases Pbuf (dead)
    _Float16* phT = (_Float16*)bB;
    float* x  = (float*)(bB + (size_t)NIPP * B_ * 2);
    float* r  = (float*)(bB + (size_t)NIPP * B_ * 2 + (size_t)NIPP * B_ * 4);
    float* rr = (float*)(bB + (size_t)NIPP * B_ * 2 + (size_t)NIPP * B_ * 8);

    k_conv<<<dim3(E_ / 64, NIPP / 64), 256, 0, stream>>>(d0, w, ii, AT);
    k_gpart<<<dim3(NTILE, 2), 256, 0, stream>>>(AT, Pbuf);
    k_comb<<<NTILE, 256, 0, stream>>>(Pbuf, s0i, ii, Sh);
    k_init<<<64, 256, 0, stream>>>(X, s0i, ii, r, phT, x, rr);

    for (int it = 0; it < NIT; ++it) {
        k_mv<<<dim3(64, KS_), 256, 0, stream>>>(Sh, phT, part, papB);
        k_fused<<<64, 1024, 0, stream>>>(part, papB, phT, x, r, rr, out,
                                         it == NIT - 1 ? 1 : 0);
    }
}

// Round 14
// 582.716 us; speedup vs baseline: 1.0908x; 1.0908x over previous
//
#include <hip/hip_runtime.h>
#include <math.h>

// V=4096, E=12288, NI=3900, B=64
#define NI_   3900
#define NIPP  4096
#define E_    12288
#define B_    64
#define V_    4096
#define NIT   8               // CG iterations (absmax 1.22e-3 vs thr 2.02e-3)
#define KS_   8               // k-splits in CG matvec (512 k each)
#define TRI   31              // live 128-tiles per dim (rows >= 3968 are zero)
#define NTILE 496             // TRI*(TRI+1)/2, = 8*62 (bijective XCD swizzle)
#define KHALF 6144            // E/2 per gemm k-split

typedef _Float16 f16x8 __attribute__((ext_vector_type(8)));
typedef _Float16 f16x4 __attribute__((ext_vector_type(4)));
typedef float    f32x4 __attribute__((ext_vector_type(4)));

__device__ __forceinline__ void gload16(const void* g, void* lds) {
    __builtin_amdgcn_global_load_lds(
        (const __attribute__((address_space(1))) unsigned int*)g,
        (__attribute__((address_space(3))) unsigned int*)lds, 16, 0, 0);
}

// wg (0..495) -> upper-triangular tile (bi, bj) over 31x31, XCD-swizzled
__device__ __forceinline__ void tile_of(int wg, int& bi, int& bj) {
    int swz = (wg & 7) * 62 + (wg >> 3);        // 496 = 8*62, bijective
    int b = 0, rem = swz;
    while (rem >= TRI - b) { rem -= TRI - b; ++b; }
    bi = b; bj = b + rem;
}

// ---------------------------------------------------------------------------
// AT[i][k] = f16( sqrt(w[k]) * d0[k, ii[i]] ), zero-padded to row 3967.
// Grid y = 62 tiles: rows 0..3967 (exactly what k_gpart reads).
__global__ __launch_bounds__(256) void k_conv(const float* __restrict__ d0,
                                              const float* __restrict__ w,
                                              const int* __restrict__ ii,
                                              _Float16* __restrict__ AT) {
    __shared__ _Float16 Ls[64][65];
    int k0 = blockIdx.x * 64, i0 = blockIdx.y * 64;
    int t = threadIdx.x;
    int kr = t >> 4, ic = (t & 15) * 4;
    int g[4];
#pragma unroll
    for (int u = 0; u < 4; ++u) {
        int i = i0 + ic + u;
        g[u] = (i < NI_) ? ii[i] : -1;
    }
    bool cont = (g[0] >= 0) && (g[3] == g[0] + 3) && ((g[0] & 3) == 0);
#pragma unroll
    for (int p = 0; p < 4; ++p) {
        int k = k0 + p * 16 + kr;
        float s = sqrtf(w[k]);
        const float* row = d0 + (size_t)k * V_;
        if (cont) {
            float4 v4 = *(const float4*)&row[g[0]];
            Ls[p * 16 + kr][ic + 0] = (_Float16)(s * v4.x);
            Ls[p * 16 + kr][ic + 1] = (_Float16)(s * v4.y);
            Ls[p * 16 + kr][ic + 2] = (_Float16)(s * v4.z);
            Ls[p * 16 + kr][ic + 3] = (_Float16)(s * v4.w);
        } else {
#pragma unroll
            for (int u = 0; u < 4; ++u)
                Ls[p * 16 + kr][ic + u] = (_Float16)(g[u] >= 0 ? s * row[g[u]] : 0.f);
        }
    }
    __syncthreads();
    int ir = t >> 3, kc = (t & 7) * 8;
#pragma unroll
    for (int p = 0; p < 2; ++p) {
        int i = p * 32 + ir;
        f16x8 v;
#pragma unroll
        for (int j = 0; j < 8; ++j) v[j] = Ls[kc + j][i];
        *(f16x8*)&AT[(size_t)(i0 + i) * E_ + k0 + kc] = v;
    }
}

// ---------------------------------------------------------------------------
// Partial S: Pbuf[ks][wg][r][c] = sum_{k in split ks} AT[gi+r,k]*AT[gj+c,k].
// m97 structure, BK=64; grid (496, 2) = 992 blocks. [R7/R9/R12-proven]
__global__ __launch_bounds__(256) void k_gpart(const _Float16* __restrict__ AT,
                                               _Float16* __restrict__ Pbuf) {
    int bi, bj; tile_of(blockIdx.x, bi, bj);
    int ks = blockIdx.y;

    __shared__ _Float16 TA[128 * 64];
    __shared__ _Float16 TB[128 * 64];
    int t = threadIdx.x, l = t & 63, w = t >> 6;
    int gi = bi * 128, gj = bj * 128;
    int wr = (w >> 1) * 64, wc = (w & 1) * 64;
    int lr = l >> 3, lc = (l & 7) * 8;

    f32x4 acc[4][4] = {};

    for (int kt = 0; kt < KHALF / 64; ++kt) {
        int k0 = ks * KHALF + kt * 64;
        if (kt) __syncthreads();
#pragma unroll
        for (int inst = 0; inst < 4; ++inst) {
            int row = w * 32 + inst * 8;
            gload16(&AT[(size_t)(gi + row + lr) * E_ + k0 + lc], &TA[row * 64]);
            gload16(&AT[(size_t)(gj + row + lr) * E_ + k0 + lc], &TB[row * 64]);
        }
        __syncthreads();
#pragma unroll
        for (int kk = 0; kk < 2; ++kk) {
            int ko = kk * 32 + (l >> 4) * 8;
            f16x8 a[4], b[4];
#pragma unroll
            for (int f = 0; f < 4; ++f) {
                a[f] = *(const f16x8*)&TA[(wr + f * 16 + (l & 15)) * 64 + ko];
                b[f] = *(const f16x8*)&TB[(wc + f * 16 + (l & 15)) * 64 + ko];
            }
#pragma unroll
            for (int fm = 0; fm < 4; ++fm)
#pragma unroll
                for (int fn = 0; fn < 4; ++fn)
                    acc[fm][fn] = __builtin_amdgcn_mfma_f32_16x16x32_f16(
                        a[fm], b[fn], acc[fm][fn], 0, 0, 0);
        }
    }
    _Float16* P = Pbuf + ((size_t)ks * NTILE + blockIdx.x) * 16384;
#pragma unroll
    for (int fm = 0; fm < 4; ++fm)
#pragma unroll
        for (int fn = 0; fn < 4; ++fn)
#pragma unroll
            for (int q = 0; q < 4; ++q) {
                int r = wr + fm * 16 + (l >> 4) * 4 + q;
                int c = wc + fn * 16 + (l & 15);
                P[r * 128 + c] = (_Float16)acc[fm][fn][q];
            }
}

// ---------------------------------------------------------------------------
// Fused: blocks 0..495 combine partials -> Sh (+diag, +mirror);
//        blocks 496..559 do CG init for column c = blockIdx - 496.
// No aliasing: Pbuf (region B) is only read; Sh/phT/x/r/rr live in region A.
__global__ __launch_bounds__(256) void k_cinit(const _Float16* __restrict__ Pbuf,
                                               const float* __restrict__ s0i,
                                               const int* __restrict__ ii,
                                               _Float16* __restrict__ Sh,
                                               const float* __restrict__ X,
                                               float* __restrict__ r,
                                               _Float16* __restrict__ phT,
                                               float* __restrict__ x,
                                               float* __restrict__ rr) {
    __shared__ _Float16 L[128][129];
    __shared__ float red[4];
    int t = threadIdx.x;

    if (blockIdx.x >= NTILE) {
        // ---- init branch
        int c = blockIdx.x - NTILE;
        float acc = 0.f;
        for (int i = t; i < NIPP; i += 256) {
            float v = 0.f;
            if (i < NI_) { int g = ii[i]; v = X[(size_t)c * V_ + g] / s0i[g]; }
            size_t o = (size_t)c * NIPP + i;
            r[o] = v; phT[o] = (_Float16)v; x[o] = 0.f;
            acc += v * v;
        }
#pragma unroll
        for (int s = 32; s; s >>= 1) acc += __shfl_down(acc, s, 64);
        if ((t & 63) == 0) red[t >> 6] = acc;
        __syncthreads();
        if (t == 0) rr[c] = red[0] + red[1] + red[2] + red[3];
        return;
    }

    // ---- combine branch
    int wg = blockIdx.x;
    int bi, bj; tile_of(wg, bi, bj);
    int gi = bi * 128, gj = bj * 128;
    const _Float16* P0 = Pbuf + (size_t)wg * 16384;
    const _Float16* P1 = Pbuf + ((size_t)NTILE + wg) * 16384;
#pragma unroll
    for (int rep = 0; rep < 16; ++rep) {
        int idx = rep * 1024 + t * 4;
        int rw = idx >> 7, c = idx & 127;
        f16x4 a = *(const f16x4*)&P0[idx];
        f16x4 b = *(const f16x4*)&P1[idx];
        f16x4 h;
#pragma unroll
        for (int u = 0; u < 4; ++u) {
            float v = (float)a[u] + (float)b[u];
            if (bi == bj && rw == c + u && gi + rw < NI_)
                v += 1.0f / s0i[ii[gi + rw]];
            h[u] = (_Float16)v;
            L[rw][c + u] = h[u];
        }
        *(f16x4*)&Sh[(size_t)(gi + rw) * NIPP + gj + c] = h;
    }
    if (bi != bj) {
        __syncthreads();
#pragma unroll
        for (int rep = 0; rep < 16; ++rep) {
            int idx = rep * 1024 + t * 4;
            int rw = idx >> 7, c = idx & 127;
            f16x4 h;
#pragma unroll
            for (int u = 0; u < 4; ++u) h[u] = L[c + u][rw];
            *(f16x4*)&Sh[(size_t)(gj + rw) * NIPP + gi + c] = h;
        }
    }
}

// ---------------------------------------------------------------------------
// part[ks][c][i] (f16) = Sh-slice @ p; pAp partials -> papB. Non-atomic.
__global__ __launch_bounds__(256) void k_mv(const _Float16* __restrict__ Sh,
                                            const _Float16* __restrict__ phT,
                                            _Float16* __restrict__ part,
                                            float* __restrict__ papB) {
    __shared__ float papL[4][64];
    int rt = blockIdx.x, ks = blockIdx.y;
    int b = ks * 64 + rt;
    int t = threadIdx.x, l = t & 63, w = t >> 6;
    int r0 = rt * 64 + w * 16;
    int lrow = l & 15, lko = (l >> 4) * 8;
    const _Float16* arow = Sh + (size_t)(r0 + lrow) * NIPP + ks * 512 + lko;
    f32x4 acc[4] = {};
#pragma unroll 4
    for (int kk = 0; kk < 16; ++kk) {
        f16x8 a = *(const f16x8*)(arow + kk * 32);
#pragma unroll
        for (int fn = 0; fn < 4; ++fn) {
            f16x8 bb = *(const f16x8*)&phT[(size_t)(fn * 16 + lrow) * NIPP +
                                           ks * 512 + kk * 32 + lko];
            acc[fn] = __builtin_amdgcn_mfma_f32_16x16x32_f16(a, bb, acc[fn], 0, 0, 0);
        }
    }
    float papv[4];
#pragma unroll
    for (int fn = 0; fn < 4; ++fn) {
        int cc = fn * 16 + lrow;
        int ro = r0 + (l >> 4) * 4;
        f16x4 h;
#pragma unroll
        for (int u = 0; u < 4; ++u) h[u] = (_Float16)acc[fn][u];
        *(f16x4*)&part[(size_t)(ks * 64 + cc) * NIPP + ro] = h;
        f16x4 pv = *(const f16x4*)&phT[(size_t)cc * NIPP + ro];
        float d = (float)pv[0] * acc[fn][0] + (float)pv[1] * acc[fn][1] +
                  (float)pv[2] * acc[fn][2] + (float)pv[3] * acc[fn][3];
        d += __shfl_xor(d, 16, 64);
        d += __shfl_xor(d, 32, 64);
        papv[fn] = d;
    }
    if (l < 16) {
#pragma unroll
        for (int fn = 0; fn < 4; ++fn) papL[w][fn * 16 + l] = papv[fn];
    }
    __syncthreads();
    if (t < 64)
        papB[(size_t)t * 512 + b] = papL[0][t] + papL[1][t] + papL[2][t] + papL[3][t];
}

// One 1024-thread block per column c: single float4 pass, registers carried.
// i >= NI_ is masked to keep padded r/p exactly zero.
__global__ __launch_bounds__(1024) void k_fused(const _Float16* __restrict__ part,
                                                const float* __restrict__ papB,
                                                _Float16* __restrict__ phT,
                                                float* __restrict__ x,
                                                float* __restrict__ r,
                                                float* __restrict__ rr,
                                                float* __restrict__ out,
                                                int last) {
    __shared__ float redA[16], redB[16];
    int c = blockIdx.x, t = threadIdx.x, l = t & 63, w = t >> 6;
    size_t cb = (size_t)c * NIPP;
    float rro = rr[c];

    float pv2 = (t < 512) ? papB[(size_t)c * 512 + t] : 0.f;
#pragma unroll
    for (int s = 32; s; s >>= 1) pv2 += __shfl_down(pv2, s, 64);
    if (l == 0) redA[w] = pv2;
    __syncthreads();
    float pap = 0.f;
#pragma unroll
    for (int k = 0; k < 16; ++k) pap += redA[k];
    float alpha = rro / (pap + 1e-30f);

    int i0 = t * 4;                          // 1024 thr x 4 = NIPP, one pass
    float sp[4] = {0.f, 0.f, 0.f, 0.f};
#pragma unroll
    for (int ks = 0; ks < KS_; ++ks) {
        f16x4 s4 = *(const f16x4*)&part[(size_t)(ks * 64 + c) * NIPP + i0];
#pragma unroll
        for (int u = 0; u < 4; ++u) sp[u] += (float)s4[u];
    }
    f16x4 p4 = *(const f16x4*)&phT[cb + i0];
    float4 x4 = *(const float4*)&x[cb + i0];
    float4 r4 = *(const float4*)&r[cb + i0];
    float pv[4] = {(float)p4[0], (float)p4[1], (float)p4[2], (float)p4[3]};
    float rv[4] = {r4.x, r4.y, r4.z, r4.w};
    float xn[4], rn[4];
    float rracc = 0.f;
#pragma unroll
    for (int u = 0; u < 4; ++u) {
        bool live = (i0 + u) < NI_;
        xn[u] = live ? (((const float*)&x4)[u] + alpha * pv[u]) : 0.f;
        rn[u] = live ? (rv[u] - alpha * sp[u]) : 0.f;
        rracc += rn[u] * rn[u];
    }
    if (last) {
        if (i0 + 3 < NI_) {   // NI_ = 3900: threads t<975 write, rest skip
            float4 o4 = make_float4(xn[0], xn[1], xn[2], xn[3]);
            *(float4*)&out[(size_t)c * NI_ + i0] = o4;
        }
    } else {
        *(float4*)&x[cb + i0] = make_float4(xn[0], xn[1], xn[2], xn[3]);
        *(float4*)&r[cb + i0] = make_float4(rn[0], rn[1], rn[2], rn[3]);
#pragma unroll
        for (int s = 32; s; s >>= 1) rracc += __shfl_down(rracc, s, 64);
        if (l == 0) redB[w] = rracc;
        __syncthreads();
        float rrn = 0.f;
#pragma unroll
        for (int k = 0; k < 16; ++k) rrn += redB[k];
        if (t == 0) rr[c] = rrn;
        float beta = rrn / (rro + 1e-30f);
        f16x4 pn;
#pragma unroll
        for (int u = 0; u < 4; ++u) pn[u] = (_Float16)(rn[u] + beta * pv[u]);
        *(f16x4*)&phT[cb + i0] = pn;
    }
}

// ---------------------------------------------------------------------------
extern "C" void kernel_launch(void* const* d_in, const int* in_sizes, int n_in,
                              void* d_out, int out_size, void* d_ws, size_t ws_size,
                              hipStream_t stream) {
    const float* X   = (const float*)d_in[0];
    const float* d0  = (const float*)d_in[1];
    const float* w   = (const float*)d_in[2];
    const float* s0i = (const float*)d_in[3];
    const int*   ii  = (const int*)d_in[4];
    float* out = (float*)d_out;

    char* ws = (char*)d_ws;
    // Region A [0, szA): AT during build; then Sh(0..33.5M) + part(34M..38M)
    //   + papB(38M..) + CG vectors (40M..43M). Region B: Pbuf (read-only
    //   during k_cinit -> no alias with CG vectors).
    size_t szA = (size_t)NIPP * E_ * 2;                       // 100,663,296
    size_t szPbuf = (size_t)2 * NTILE * 16384 * 2;            //  32,505,856
    if (ws_size < szA + szPbuf) return;  // clean failure signal

    _Float16* AT = (_Float16*)ws;
    _Float16* Pbuf = (_Float16*)(ws + szA);

    _Float16* Sh = (_Float16*)ws;                             // aliases AT (dead)
    _Float16* part = (_Float16*)(ws + (size_t)34 * 1048576);  // 4MB f16
    float* papB = (float*)(part + (size_t)KS_ * 64 * NIPP);   // 128KB

    char* bV = ws + (size_t)40 * 1048576;                     // CG vectors, in A
    _Float16* phT = (_Float16*)bV;
    float* x  = (float*)(bV + (size_t)NIPP * B_ * 2);
    float* r  = (float*)(bV + (size_t)NIPP * B_ * 2 + (size_t)NIPP * B_ * 4);
    float* rr = (float*)(bV + (size_t)NIPP * B_ * 2 + (size_t)NIPP * B_ * 8);

    k_conv<<<dim3(E_ / 64, 62), 256, 0, stream>>>(d0, w, ii, AT);
    k_gpart<<<dim3(NTILE, 2), 256, 0, stream>>>(AT, Pbuf);
    k_cinit<<<NTILE + 64, 256, 0, stream>>>(Pbuf, s0i, ii, Sh, X, r, phT, x, rr);

    for (int it = 0; it < NIT; ++it) {
        k_mv<<<dim3(64, KS_), 256, 0, stream>>>(Sh, phT, part, papB);
        k_fused<<<64, 1024, 0, stream>>>(part, papB, phT, x, r, rr, out,
                                         it == NIT - 1 ? 1 : 0);
    }
}